// Round 10
// baseline (144.340 us; speedup 1.0000x reference)
//
#include <hip/hip_runtime.h>

// NonImagingRod: per-ray damped-Newton (LM) root find on f(t) = A t^2 + B t + C.
// Round-10: R8's proven 2-chunk pipeline skeleton (43.4 us, no spill), with
// the inner loop in PACKED fp32 (v2f -> v_pk_fma_f32/v_pk_mul_f32): 16 insts
// per 4-ray iteration vs 28 scalar. Rationale: VALUBusy pins at ~50% in every
// well-fed config (R1/R7/R8/R9) across different op counts — consistent with
// VALU issue saturation (wave64 = 2 datapath-cyc but 1 issue count on
// SIMD-32). At issue saturation, duration ∝ instruction count -> pack.
//
// Codegen notes (hard-won):
//  - The R2/R3 "v2f causes spills" theory was WRONG: R4 spilled identically
//    with scalar code. The spill wall is the 8-SIMULTANEOUSLY-ITERATED-ray
//    live set. 4 iterated rays (as 2 v2f pairs, 12 state VGPRs) + 24 prefetch
//    regs is the proven-clean budget (R8: VGPR 32, FETCH stable).
//  - No-spill signature: FETCH_SIZE stable ~49-50 MB (SGPR count is NOT one).
//  - Pipeline depth 2 is enough (R9's depth-4 was neutral); keep 2048 blocks.
//  - Clamp(+-1000) provably inactive; rcp ~1ulp fine (absmax 0.0, R2-R9).

#define LM_ITERS 31
constexpr float DAMPING = 0.5f;

typedef float v2f __attribute__((ext_vector_type(2)));

__global__ __launch_bounds__(256) void rod_kernel(
    const float* __restrict__ P, const float* __restrict__ V,
    const float* __restrict__ Rm, const float* __restrict__ Tv,
    const float* __restrict__ c_ptr, double* __restrict__ ws, int n)
{
    const float c  = c_ptr[0];
    const float r00 = Rm[0], r01 = Rm[1], r02 = Rm[2];
    const float r10 = Rm[3], r11 = Rm[4], r12 = Rm[5];
    const float r20 = Rm[6], r21 = Rm[7], r22 = Rm[8];
    const float t0 = Tv[0], t1 = Tv[1], t2 = Tv[2];

    const int tid      = blockIdx.x * blockDim.x + threadIdx.x;
    const int nthreads = gridDim.x * blockDim.x;
    const int g0 = tid;                 // chunk 0: rays [4*g0, 4*g0+4)
    const int g1 = tid + nthreads;      // chunk 1: rays [4*g1, 4*g1+4)

    const float4* P4 = (const float4*)P;
    const float4* V4 = (const float4*)V;

    double acc = 0.0;

    // State: 4 rays as 2 packed pairs.
    v2f nA0, nA1, f0, f1, fp0, fp1;

    auto setup4 = [&](const float4& qa, const float4& qb, const float4& qc,
                      const float4& ua, const float4& ub, const float4& uc) {
        const float px[4] = {qa.x, qa.w, qb.z, qc.y};
        const float py[4] = {qa.y, qb.x, qb.w, qc.z};
        const float pz[4] = {qa.z, qb.y, qc.x, qc.w};
        const float wx[4] = {ua.x, ua.w, ub.z, uc.y};
        const float wy[4] = {ua.y, ub.x, ub.w, uc.z};
        const float wz[4] = {ua.z, ub.y, uc.x, uc.w};
        #pragma unroll
        for (int r = 0; r < 4; ++r) {
            const float qx = px[r] - t0, qy = py[r] - t1, qz = pz[r] - t2;
            const float plx = qx * r00 + qy * r10 + qz * r20;
            const float ply = qx * r01 + qy * r11 + qz * r21;
            const float plz = qx * r02 + qy * r12 + qz * r22;
            const float vlx = wx[r] * r00 + wy[r] * r10 + wz[r] * r20;
            const float vly = wx[r] * r01 + wy[r] * r11 + wz[r] * r21;
            const float vlz = wx[r] * r02 + wy[r] * r12 + wz[r] * r22;
            const float na = c * (vly * vly + vlz * vlz);               // -A
            const float fv = plx - c * (ply * ply + plz * plz);         // f(0)
            const float fq = vlx - 2.0f * c * (ply * vly + plz * vlz);  // f'(0)
            if (r < 2) { nA0[r & 1] = na; f0[r & 1] = fv; fp0[r & 1] = fq; }
            else       { nA1[r & 1] = na; f1[r & 1] = fv; fp1[r & 1] = fq; }
        }
    };

    // Packed LM step (exact quadratic Taylor update):
    //   den = fp*fp + damping;  d = (f*fp) * rcp(den)
    //   tmp = fp - A*d;  f <- f - d*tmp;  fp <- tmp - A*d
    const v2f vdamp = {DAMPING, DAMPING};
    auto iterate = [&]() {
        #pragma unroll 1
        for (int it = 0; it < LM_ITERS; ++it) {
            {
                const v2f den = __builtin_elementwise_fma(fp0, fp0, vdamp);
                v2f rcp;
                rcp.x = __builtin_amdgcn_rcpf(den.x);   // ~1 ulp; LM self-corrects
                rcp.y = __builtin_amdgcn_rcpf(den.y);
                const v2f d   = (f0 * fp0) * rcp;
                const v2f tmp = __builtin_elementwise_fma(nA0, d, fp0);
                f0  = __builtin_elementwise_fma(-d, tmp, f0);
                fp0 = __builtin_elementwise_fma(nA0, d, tmp);
            }
            {
                const v2f den = __builtin_elementwise_fma(fp1, fp1, vdamp);
                v2f rcp;
                rcp.x = __builtin_amdgcn_rcpf(den.x);
                rcp.y = __builtin_amdgcn_rcpf(den.y);
                const v2f d   = (f1 * fp1) * rcp;
                const v2f tmp = __builtin_elementwise_fma(nA1, d, fp1);
                f1  = __builtin_elementwise_fma(-d, tmp, f1);
                fp1 = __builtin_elementwise_fma(nA1, d, tmp);
            }
        }
    };

    auto accum = [&](int g) {
        if (4 * g + 4 <= n) {           // full chunk: no per-ray compares
            acc += (double)f0.x * (double)f0.x + (double)f0.y * (double)f0.y;
            acc += (double)f1.x * (double)f1.x + (double)f1.y * (double)f1.y;
        } else {
            const float fs[4] = {f0.x, f0.y, f1.x, f1.y};
            for (int r = 0; r < 4; ++r)
                if (4 * g + r < n) acc += (double)fs[r] * (double)fs[r];
        }
    };

    // ---- chunk 0 load ----
    float4 a0{}, b0{}, c0{}, u0{}, v0{}, w0{};
    if (4 * g0 < n) {
        a0 = P4[g0 * 3 + 0]; b0 = P4[g0 * 3 + 1]; c0 = P4[g0 * 3 + 2];
        u0 = V4[g0 * 3 + 0]; v0 = V4[g0 * 3 + 1]; w0 = V4[g0 * 3 + 2];
    }
    setup4(a0, b0, c0, u0, v0, w0);

    // ---- prefetch chunk 1 (independent: overlaps chunk-0 loop) ----
    float4 a1{}, b1{}, c1{}, u1{}, v1{}, w1{};
    const bool has1 = (4 * g1 < n);
    if (has1) {
        a1 = P4[g1 * 3 + 0]; b1 = P4[g1 * 3 + 1]; c1 = P4[g1 * 3 + 2];
        u1 = V4[g1 * 3 + 0]; v1 = V4[g1 * 3 + 1]; w1 = V4[g1 * 3 + 2];
    }

    iterate();                           // chunk 0
    if (4 * g0 < n) accum(g0);

    setup4(a1, b1, c1, u1, v1, w1);
    iterate();                           // chunk 1
    if (has1) accum(g1);

    // wave(64) shuffle reduce -> LDS across 4 waves -> one f64 atomic per block
    for (int off = 32; off > 0; off >>= 1)
        acc += __shfl_down(acc, off, 64);
    __shared__ double sacc[4];
    const int lane = threadIdx.x & 63, wave = threadIdx.x >> 6;
    if (lane == 0) sacc[wave] = acc;
    __syncthreads();
    if (threadIdx.x == 0) {
        atomicAdd(ws, sacc[0] + sacc[1] + sacc[2] + sacc[3]);
    }
}

__global__ void rod_finalize(const double* __restrict__ ws,
                             const float* __restrict__ loss_in,
                             float* __restrict__ out, double inv_n)
{
    out[0] = (float)(ws[0] * inv_n + (double)loss_in[0]);
}

extern "C" void kernel_launch(void* const* d_in, const int* in_sizes, int n_in,
                              void* d_out, int out_size, void* d_ws, size_t ws_size,
                              hipStream_t stream) {
    const float* P       = (const float*)d_in[0];
    const float* V       = (const float*)d_in[1];
    const float* R       = (const float*)d_in[2];
    const float* T       = (const float*)d_in[3];
    const float* c       = (const float*)d_in[4];
    const float* loss_in = (const float*)d_in[5];

    const int n = in_sizes[0] / 3;           // number of rays

    // d_ws is poisoned to 0xAA before every launch — zero the accumulator.
    hipMemsetAsync(d_ws, 0, sizeof(double), stream);

    // 8 rays/thread as 2 pipelined 4-ray chunks (R8's proven grid: 2048 blocks).
    const int threads = (n + 7) / 8;
    const int block   = 256;
    const int grid    = (threads + block - 1) / block;
    rod_kernel<<<grid, block, 0, stream>>>(P, V, R, T, c, (double*)d_ws, n);
    rod_finalize<<<1, 1, 0, stream>>>((const double*)d_ws, loss_in,
                                      (float*)d_out, 1.0 / (double)n);
}

// Round 11
// 139.330 us; speedup vs baseline: 1.0360x; 1.0360x over previous
//
#include <hip/hip_runtime.h>

// NonImagingRod: per-ray damped-Newton (LM) root find on f(t) = A t^2 + B t + C.
// Round-11: R8's proven 2-chunk pipeline skeleton; iterate() rewritten
// STAGE-WISE (all dens, all rcps, all nums, ...) so the 4 independent ray
// chains interleave instead of executing serially at dependent-op latency.
// Evidence: R8/R9/R10 all pin at 43.4us = ~210 cyc per 4-ray iter = ~6-7 cyc
// per inst = serial chains; the pressure-minimizing scheduler keeps each
// ray's chain contiguous to hold VGPR at 32-36. Stage-form source gives it
// the interleaved schedule for free (live peak ~28-40 VGPR, still clean).
//
// Codegen notes (hard-won):
//  - 8 SIMULTANEOUSLY-iterated rays: spill wall (R2-5). 4 iterated + 24
//    prefetch regs is proven clean (R8: VGPR 32, FETCH stable 49.2 MB).
//  - No-spill signature: FETCH_SIZE stable ~49-50 MB.
//  - v_pk_* is a dead end on CDNA4: fp32 peak = plain wave64 v_fma at 2cyc;
//    packing halves issue slots only (R10 neutral).
//  - Pipeline depth 2 suffices (R9 depth-4 neutral). 2048 blocks.
//  - Clamp(+-1000) provably inactive; rcp ~1ulp fine (absmax 0.0, R2-R10).

#define LM_ITERS 31
constexpr float DAMPING = 0.5f;

__global__ __launch_bounds__(256) void rod_kernel(
    const float* __restrict__ P, const float* __restrict__ V,
    const float* __restrict__ Rm, const float* __restrict__ Tv,
    const float* __restrict__ c_ptr, double* __restrict__ ws, int n)
{
    const float c  = c_ptr[0];
    const float r00 = Rm[0], r01 = Rm[1], r02 = Rm[2];
    const float r10 = Rm[3], r11 = Rm[4], r12 = Rm[5];
    const float r20 = Rm[6], r21 = Rm[7], r22 = Rm[8];
    const float t0 = Tv[0], t1 = Tv[1], t2 = Tv[2];

    const int tid      = blockIdx.x * blockDim.x + threadIdx.x;
    const int nthreads = gridDim.x * blockDim.x;
    const int g0 = tid;                 // chunk 0: rays [4*g0, 4*g0+4)
    const int g1 = tid + nthreads;      // chunk 1: rays [4*g1, 4*g1+4)

    const float4* P4 = (const float4*)P;
    const float4* V4 = (const float4*)V;

    double acc = 0.0;

    float nA[4], f[4], fp[4];
    auto setup4 = [&](const float4& qa, const float4& qb, const float4& qc,
                      const float4& ua, const float4& ub, const float4& uc) {
        const float px[4] = {qa.x, qa.w, qb.z, qc.y};
        const float py[4] = {qa.y, qb.x, qb.w, qc.z};
        const float pz[4] = {qa.z, qb.y, qc.x, qc.w};
        const float wx[4] = {ua.x, ua.w, ub.z, uc.y};
        const float wy[4] = {ua.y, ub.x, ub.w, uc.z};
        const float wz[4] = {ua.z, ub.y, uc.x, uc.w};
        #pragma unroll
        for (int r = 0; r < 4; ++r) {
            const float qx = px[r] - t0, qy = py[r] - t1, qz = pz[r] - t2;
            const float plx = qx * r00 + qy * r10 + qz * r20;
            const float ply = qx * r01 + qy * r11 + qz * r21;
            const float plz = qx * r02 + qy * r12 + qz * r22;
            const float vlx = wx[r] * r00 + wy[r] * r10 + wz[r] * r20;
            const float vly = wx[r] * r01 + wy[r] * r11 + wz[r] * r21;
            const float vlz = wx[r] * r02 + wy[r] * r12 + wz[r] * r22;
            nA[r] = c * (vly * vly + vlz * vlz);                 // -A
            f[r]  = plx - c * (ply * ply + plz * plz);           // f(0)  = C
            fp[r] = vlx - 2.0f * c * (ply * vly + plz * vlz);    // f'(0) = B
        }
    };

    // Stage-interleaved LM step (exact quadratic Taylor update):
    //   den = fp^2 + damping; d = (f*fp)*rcp(den);
    //   tmp = fp - A*d; f <- f - d*tmp; fp <- tmp - A*d.
    auto iterate = [&]() {
        #pragma unroll 1
        for (int it = 0; it < LM_ITERS; ++it) {
            float den[4], w[4], num[4], d[4], tmp[4];
            #pragma unroll
            for (int r = 0; r < 4; ++r) den[r] = fmaf(fp[r], fp[r], DAMPING);
            #pragma unroll
            for (int r = 0; r < 4; ++r) w[r] = __builtin_amdgcn_rcpf(den[r]);
            #pragma unroll
            for (int r = 0; r < 4; ++r) num[r] = f[r] * fp[r];
            #pragma unroll
            for (int r = 0; r < 4; ++r) d[r] = num[r] * w[r];
            #pragma unroll
            for (int r = 0; r < 4; ++r) tmp[r] = fmaf(nA[r], d[r], fp[r]);
            #pragma unroll
            for (int r = 0; r < 4; ++r) f[r] = fmaf(-d[r], tmp[r], f[r]);
            #pragma unroll
            for (int r = 0; r < 4; ++r) fp[r] = fmaf(nA[r], d[r], tmp[r]);
        }
    };

    auto accum = [&](int g) {
        if (4 * g + 4 <= n) {
            acc += (double)f[0] * (double)f[0] + (double)f[1] * (double)f[1];
            acc += (double)f[2] * (double)f[2] + (double)f[3] * (double)f[3];
        } else {
            for (int r = 0; r < 4; ++r)
                if (4 * g + r < n) acc += (double)f[r] * (double)f[r];
        }
    };

    // ---- chunk 0 load ----
    float4 a0{}, b0{}, c0{}, u0{}, v0{}, w0{};
    if (4 * g0 < n) {
        a0 = P4[g0 * 3 + 0]; b0 = P4[g0 * 3 + 1]; c0 = P4[g0 * 3 + 2];
        u0 = V4[g0 * 3 + 0]; v0 = V4[g0 * 3 + 1]; w0 = V4[g0 * 3 + 2];
    }
    setup4(a0, b0, c0, u0, v0, w0);

    // ---- prefetch chunk 1 (independent: overlaps chunk-0 loop) ----
    float4 a1{}, b1{}, c1{}, u1{}, v1{}, w1{};
    const bool has1 = (4 * g1 < n);
    if (has1) {
        a1 = P4[g1 * 3 + 0]; b1 = P4[g1 * 3 + 1]; c1 = P4[g1 * 3 + 2];
        u1 = V4[g1 * 3 + 0]; v1 = V4[g1 * 3 + 1]; w1 = V4[g1 * 3 + 2];
    }

    iterate();                           // chunk 0
    if (4 * g0 < n) accum(g0);

    setup4(a1, b1, c1, u1, v1, w1);
    iterate();                           // chunk 1
    if (has1) accum(g1);

    // wave(64) shuffle reduce -> LDS across 4 waves -> one f64 atomic per block
    for (int off = 32; off > 0; off >>= 1)
        acc += __shfl_down(acc, off, 64);
    __shared__ double sacc[4];
    const int lane = threadIdx.x & 63, wave = threadIdx.x >> 6;
    if (lane == 0) sacc[wave] = acc;
    __syncthreads();
    if (threadIdx.x == 0) {
        atomicAdd(ws, sacc[0] + sacc[1] + sacc[2] + sacc[3]);
    }
}

__global__ void rod_finalize(const double* __restrict__ ws,
                             const float* __restrict__ loss_in,
                             float* __restrict__ out, double inv_n)
{
    out[0] = (float)(ws[0] * inv_n + (double)loss_in[0]);
}

extern "C" void kernel_launch(void* const* d_in, const int* in_sizes, int n_in,
                              void* d_out, int out_size, void* d_ws, size_t ws_size,
                              hipStream_t stream) {
    const float* P       = (const float*)d_in[0];
    const float* V       = (const float*)d_in[1];
    const float* R       = (const float*)d_in[2];
    const float* T       = (const float*)d_in[3];
    const float* c       = (const float*)d_in[4];
    const float* loss_in = (const float*)d_in[5];

    const int n = in_sizes[0] / 3;           // number of rays

    // d_ws is poisoned to 0xAA before every launch — zero the accumulator.
    hipMemsetAsync(d_ws, 0, sizeof(double), stream);

    // 8 rays/thread as 2 pipelined 4-ray chunks (R8's proven grid: 2048 blocks).
    const int threads = (n + 7) / 8;
    const int block   = 256;
    const int grid    = (threads + block - 1) / block;
    rod_kernel<<<grid, block, 0, stream>>>(P, V, R, T, c, (double*)d_ws, n);
    rod_finalize<<<1, 1, 0, stream>>>((const double*)d_ws, loss_in,
                                      (float*)d_out, 1.0 / (double)n);
}